// Round 1
// baseline (47.803 us; speedup 1.0000x reference)
//
#include <hip/hip_runtime.h>

#define B_ 2
#define L_ 256
#define H_ 256
#define A_ 32
#define P_ 64

// k1: per 4 rows r = b*L+l: compute h[r, 0..31] then g[r, a, p] = sum_c out_w[p, a*32+c] * h[r, c]
__global__ __launch_bounds__(256) void k1_proj(
    const float* __restrict__ x,     // [B,L,H]
    const float* __restrict__ in_w,  // [A,H]
    const float* __restrict__ in_b,  // [A]
    const float* __restrict__ out_w, // [P, A*A]
    float* __restrict__ g,           // [B*L, A, P]
    float* __restrict__ hg)          // [B*L, A]
{
    __shared__ float xs[4 * H_];     // 4 input rows
    __shared__ float hl[4][A_];
    const int t = threadIdx.x;
    const int r0 = blockIdx.x * 4;

    // stage 4 rows of x (1024 floats = 256 float4)
    {
        const float4* src = (const float4*)(x + (size_t)r0 * H_);
        float4* dst = (float4*)xs;
        dst[t] = src[t];
    }
    __syncthreads();

    // h: 4 rows x 32 outputs, 2 threads per dot of length 256
    {
        const int jj = t >> 6;        // row 0..3 (one wave per row)
        const int rem = t & 63;
        const int a = rem >> 1;       // 0..31
        const int half = rem & 1;
        const float4* w4 = (const float4*)(in_w + a * H_ + half * 128);
        const float4* xv4 = (const float4*)(xs + jj * H_ + half * 128);
        float s = 0.f;
        #pragma unroll
        for (int m = 0; m < 32; ++m) {
            float4 w = w4[m];
            float4 xv = xv4[m];
            s += w.x * xv.x + w.y * xv.y + w.z * xv.z + w.w * xv.w;
        }
        s += __shfl_xor(s, 1);
        if (half == 0) {
            float hv = s + in_b[a];
            hl[jj][a] = hv;
            hg[(r0 + jj) * A_ + a] = hv;
        }
    }
    __syncthreads();

    // g[r, a, p]: thread owns p = t&63, a-range (t>>6)*8 .. +7
    const int p = t & 63;
    const int ag = t >> 6;   // 0..3
    #pragma unroll
    for (int k = 0; k < 8; ++k) {
        const int a = ag * 8 + k;
        const float4* wrow = (const float4*)(out_w + (size_t)p * (A_ * A_) + a * A_);
        float4 w[8];
        #pragma unroll
        for (int m = 0; m < 8; ++m) w[m] = wrow[m];
        #pragma unroll
        for (int jj = 0; jj < 4; ++jj) {
            const float* hh = hl[jj];   // uniform address -> LDS broadcast
            float s = 0.f;
            #pragma unroll
            for (int m = 0; m < 8; ++m) {
                s += w[m].x * hh[4*m]   + w[m].y * hh[4*m+1]
                   + w[m].z * hh[4*m+2] + w[m].w * hh[4*m+3];
            }
            g[((size_t)(r0 + jj) * A_ + a) * P_ + p] = s;   // coalesced over p
        }
    }
}

// k2: tile 16 i x 16 j x 64 p; out[b,i,j,p] = sum_a h[b,i,a]*g[b,j,a,p] + biases + pos
__global__ __launch_bounds__(256) void k2_outer(
    const float* __restrict__ g,      // [B*L, A, P]
    const float* __restrict__ hg,     // [B*L, A]
    const float* __restrict__ out_b,  // [P]
    const float* __restrict__ pos_w,  // [P,17]
    const float* __restrict__ pos_b,  // [P]
    float* __restrict__ out)          // [B, L, L, P]
{
    __shared__ float hs[16 * A_];     // h tile for 16 i-rows
    const int t = threadIdx.x;
    const int i0 = blockIdx.x * 16;
    const int j0 = blockIdx.y * 16;
    const int b = blockIdx.z;

    hs[t]       = hg[(b * L_ + i0) * A_ + t];
    hs[t + 256] = hg[(b * L_ + i0) * A_ + t + 256];
    __syncthreads();

    const int pq = t & 15;            // p-quadrant first -> coalesced stores
    const int jl = t >> 4;
    const int p4 = pq * 4;
    const int j = j0 + jl;

    const float4* gp = (const float4*)(g + (size_t)(b * L_ + j) * (A_ * P_) + p4);
    float4 acc[16];
    #pragma unroll
    for (int il = 0; il < 16; ++il) acc[il] = make_float4(0.f, 0.f, 0.f, 0.f);

    #pragma unroll
    for (int a0 = 0; a0 < A_; a0 += 4) {
        float4 ga0 = gp[(a0 + 0) * (P_ / 4)];
        float4 ga1 = gp[(a0 + 1) * (P_ / 4)];
        float4 ga2 = gp[(a0 + 2) * (P_ / 4)];
        float4 ga3 = gp[(a0 + 3) * (P_ / 4)];
        #pragma unroll
        for (int il = 0; il < 16; ++il) {
            float4 h4 = *(const float4*)(hs + il * A_ + a0);  // uniform -> broadcast
            acc[il].x += h4.x * ga0.x + h4.y * ga1.x + h4.z * ga2.x + h4.w * ga3.x;
            acc[il].y += h4.x * ga0.y + h4.y * ga1.y + h4.z * ga2.y + h4.w * ga3.y;
            acc[il].z += h4.x * ga0.z + h4.y * ga1.z + h4.z * ga2.z + h4.w * ga3.z;
            acc[il].w += h4.x * ga0.w + h4.y * ga1.w + h4.z * ga2.w + h4.w * ga3.w;
        }
    }

    float4 bias;
    bias.x = out_b[p4 + 0] + pos_b[p4 + 0];
    bias.y = out_b[p4 + 1] + pos_b[p4 + 1];
    bias.z = out_b[p4 + 2] + pos_b[p4 + 2];
    bias.w = out_b[p4 + 3] + pos_b[p4 + 3];

    float4* op = (float4*)(out + (((size_t)(b * L_ + i0)) * L_ + j) * P_ + p4);
    #pragma unroll
    for (int il = 0; il < 16; ++il) {
        int d = (i0 + il) - j;
        d = d < -8 ? -8 : (d > 8 ? 8 : d);
        d += 8;
        float4 v;
        v.x = acc[il].x + bias.x + pos_w[(p4 + 0) * 17 + d];
        v.y = acc[il].y + bias.y + pos_w[(p4 + 1) * 17 + d];
        v.z = acc[il].z + bias.z + pos_w[(p4 + 2) * 17 + d];
        v.w = acc[il].w + bias.w + pos_w[(p4 + 3) * 17 + d];
        op[(size_t)il * (L_ * P_ / 4)] = v;
    }
}

extern "C" void kernel_launch(void* const* d_in, const int* in_sizes, int n_in,
                              void* d_out, int out_size, void* d_ws, size_t ws_size,
                              hipStream_t stream) {
    const float* x     = (const float*)d_in[0];
    const float* in_w  = (const float*)d_in[1];
    const float* in_b  = (const float*)d_in[2];
    const float* out_w = (const float*)d_in[3];
    const float* out_b = (const float*)d_in[4];
    const float* pos_w = (const float*)d_in[5];
    const float* pos_b = (const float*)d_in[6];
    float* out = (float*)d_out;

    float* g  = (float*)d_ws;                                          // 4 MB
    float* hg = (float*)((char*)d_ws + (size_t)B_ * L_ * A_ * P_ * 4); // 64 KB

    k1_proj<<<dim3((B_ * L_) / 4), 256, 0, stream>>>(x, in_w, in_b, out_w, g, hg);
    k2_outer<<<dim3(L_ / 16, L_ / 16, B_), 256, 0, stream>>>(g, hg, out_b, pos_w, pos_b, out);
}